// Round 1
// baseline (820.942 us; speedup 1.0000x reference)
//
#include <hip/hip_runtime.h>
#include <hip/hip_bf16.h>

// NegSamplerMiniBatch: out[n] = centroids[ idx of 2nd-largest distance(x_n, c_k) ]
// N=262144, D=256, K=256, f32.
//
// Ranking key per row n: s_k = |c_k|^2 - 2 * x_n . c_k   (x2, sqrt, clamp are
// rank-monotone). f32 GEMM + top-3 gap test; ambiguous rows (gap < EPS) are
// exactly re-ranked in f64 by refine_kernel. EPS=0.02 >> worst-case f32 dot
// error (~8e-3 bound, ~2e-4 typical), so the final selection is f64-exact.

#define TM 64          // rows per block in score_kernel
#define DK 32          // D-chunk staged in LDS
#define XT_STRIDE 68   // padded (68*4B = 272B, 16B-aligned; bank-spread)
#define SC_STRIDE 97   // padded reduce stride (odd -> conflict-free column scan)
#define EPS 0.02f
#define CAP_MAX 65536

// ---------------- c2 (f64 exact + f32 copy) ----------------
__global__ __launch_bounds__(256) void c2_kernel(const float* __restrict__ C,
                                                 float* __restrict__ c2f,
                                                 double* __restrict__ c2d) {
    int k = threadIdx.x;
    const float* row = C + (size_t)k * 256;
    double s = 0.0;
    for (int d = 0; d < 256; ++d) { double v = (double)row[d]; s += v * v; }
    c2f[k] = (float)s;
    c2d[k] = s;
}

// ---------------- fused GEMM + top-3 + flag + gather-write ----------------
__global__ __launch_bounds__(256, 3) void score_kernel(
    const float* __restrict__ X, const float* __restrict__ C,
    const float* __restrict__ c2f, unsigned* __restrict__ counter,
    unsigned* __restrict__ list, unsigned cap, float* __restrict__ out) {

    // stage:   XT[DK][XT_STRIDE] (8704 B) + CT[DK][256] (32768 B) = 41472 B
    // reduce:  scl[64][SC_STRIDE] f32 (24832 B) + idl[64][SC_STRIDE] i32 (24832 B)
    __shared__ __align__(16) char SH[49664];
    __shared__ float c2s[256];
    __shared__ int bestIdx[64];

    float* XT  = (float*)SH;            // [d][r], stride XT_STRIDE
    float* CT  = (float*)(SH + 8704);   // [d][c], stride 256
    float* scl = (float*)SH;            // [row][entry], stride SC_STRIDE
    int*   idl = (int*)(SH + 24832);    // [row][entry], stride SC_STRIDE

    const int t = threadIdx.x;
    const int i = t & 31;     // centroid group: owns cents i*8 .. i*8+7
    const int j = t >> 5;     // row group:      owns rows  j*8 .. j*8+7
    const int rowBase = blockIdx.x * TM;

    c2s[t] = c2f[t];

    float acc[8][8];
    #pragma unroll
    for (int a = 0; a < 8; ++a)
        #pragma unroll
        for (int b = 0; b < 8; ++b) acc[a][b] = 0.f;

    const int lr = t >> 2;          // load row 0..63
    const int dq = (t & 3) * 8;     // 0,8,16,24

    for (int chunk = 0; chunk < 8; ++chunk) {
        const int d0 = chunk * DK;
        // global loads first (into regs), then stage
        const float4* gx = (const float4*)(X + (size_t)(rowBase + lr) * 256 + d0 + dq);
        float4 xa = gx[0], xb = gx[1];
        const float4* gc = (const float4*)(C + (size_t)t * 256 + d0);
        float4 cc[8];
        #pragma unroll
        for (int m = 0; m < 8; ++m) cc[m] = gc[m];

        __syncthreads();   // prev chunk fully consumed
        XT[(dq + 0) * XT_STRIDE + lr] = xa.x;
        XT[(dq + 1) * XT_STRIDE + lr] = xa.y;
        XT[(dq + 2) * XT_STRIDE + lr] = xa.z;
        XT[(dq + 3) * XT_STRIDE + lr] = xa.w;
        XT[(dq + 4) * XT_STRIDE + lr] = xb.x;
        XT[(dq + 5) * XT_STRIDE + lr] = xb.y;
        XT[(dq + 6) * XT_STRIDE + lr] = xb.z;
        XT[(dq + 7) * XT_STRIDE + lr] = xb.w;
        #pragma unroll
        for (int m = 0; m < 8; ++m) {
            CT[(m * 4 + 0) * 256 + t] = cc[m].x;
            CT[(m * 4 + 1) * 256 + t] = cc[m].y;
            CT[(m * 4 + 2) * 256 + t] = cc[m].z;
            CT[(m * 4 + 3) * 256 + t] = cc[m].w;
        }
        __syncthreads();

        #pragma unroll 4
        for (int d = 0; d < DK; ++d) {
            const float4* x4 = (const float4*)(XT + d * XT_STRIDE + j * 8);
            float4 x0 = x4[0], x1 = x4[1];
            const float4* c4 = (const float4*)(CT + d * 256 + i * 8);
            float4 c0 = c4[0], c1 = c4[1];
            float xr[8] = {x0.x, x0.y, x0.z, x0.w, x1.x, x1.y, x1.z, x1.w};
            float cv[8] = {c0.x, c0.y, c0.z, c0.w, c1.x, c1.y, c1.z, c1.w};
            #pragma unroll
            for (int r = 0; r < 8; ++r)
                #pragma unroll
                for (int c = 0; c < 8; ++c)
                    acc[r][c] = fmaf(xr[r], cv[c], acc[r][c]);
        }
    }
    __syncthreads();   // stage LDS dead; overlay with reduce arrays

    // per-thread top-3 over its 8 centroids, for each of its 8 rows
    #pragma unroll
    for (int rr = 0; rr < 8; ++rr) {
        float b1 = -INFINITY, b2 = -INFINITY, b3 = -INFINITY;
        int i1 = 0, i2 = 0, i3 = 0;
        #pragma unroll
        for (int cc2 = 0; cc2 < 8; ++cc2) {
            int c = i * 8 + cc2;
            float s = c2s[c] - 2.f * acc[rr][cc2];
            if (s > b1)      { b3 = b2; i3 = i2; b2 = b1; i2 = i1; b1 = s; i1 = c; }
            else if (s > b2) { b3 = b2; i3 = i2; b2 = s;  i2 = c; }
            else if (s > b3) { b3 = s;  i3 = c; }
        }
        int row = j * 8 + rr;
        int base = row * SC_STRIDE + i * 3;
        scl[base + 0] = b1; scl[base + 1] = b2; scl[base + 2] = b3;
        idl[base + 0] = i1; idl[base + 1] = i2; idl[base + 2] = i3;
    }
    __syncthreads();

    // one thread per row merges the 96 candidates
    if (t < 64) {
        float b1 = -INFINITY, b2 = -INFINITY, b3 = -INFINITY;
        int i1 = 0, i2 = 0;
        for (int ii = 0; ii < 96; ++ii) {
            float s = scl[t * SC_STRIDE + ii];
            int c = idl[t * SC_STRIDE + ii];
            if (s > b1)      { b3 = b2; b2 = b1; i2 = i1; b1 = s; i1 = c; }
            else if (s > b2) { b3 = b2; b2 = s;  i2 = c; }
            else if (s > b3) { b3 = s; }
        }
        bestIdx[t] = i2;
        // ambiguous under f32 error? -> flag for exact f64 re-rank
        if (b1 - b2 < EPS || b2 - b3 < EPS) {
            unsigned p = atomicAdd(counter, 1u);
            if (p < cap) list[p] = (unsigned)(rowBase + t);
        }
    }
    __syncthreads();

    // gather-write: 4 threads per row, 16 float4 each, lane-adjacent float4s
    {
        int r = t >> 2, q0 = t & 3;
        int c = bestIdx[r];
        const float4* src = (const float4*)(C + (size_t)c * 256);
        float4* dst = (float4*)(out + (size_t)(rowBase + r) * 256);
        #pragma unroll
        for (int q = 0; q < 16; ++q) {
            int f = q0 + 4 * q;
            dst[f] = src[f];
        }
    }
}

// ---------------- exact f64 re-rank of flagged rows ----------------
__global__ __launch_bounds__(256) void refine_kernel(
    const float* __restrict__ X, const float* __restrict__ C,
    const double* __restrict__ c2d, const unsigned* __restrict__ counter,
    const unsigned* __restrict__ list, unsigned cap, float* __restrict__ out) {

    __shared__ double sh[256];
    __shared__ int b2s;
    unsigned count = *counter;
    if (count > cap) count = cap;
    const int k = threadIdx.x;

    for (unsigned idx = blockIdx.x; idx < count; idx += gridDim.x) {
        unsigned row = list[idx];
        const float* x = X + (size_t)row * 256;
        const float* c = C + (size_t)k * 256;
        double a = 0.0;
        for (int d = 0; d < 256; ++d) a += (double)x[d] * (double)c[d];
        sh[k] = c2d[k] - 2.0 * a;
        __syncthreads();
        if (k == 0) {
            double b1 = -1e300, b2 = -1e300;
            int i1 = 0, i2 = 0;
            for (int q = 0; q < 256; ++q) {
                double s = sh[q];
                if (s > b1)      { b2 = b1; i2 = i1; b1 = s; i1 = q; }
                else if (s > b2) { b2 = s;  i2 = q; }
            }
            b2s = i2;
        }
        __syncthreads();
        int csel = b2s;
        if (k < 64) {
            const float4* src = (const float4*)(C + (size_t)csel * 256);
            float4* dst = (float4*)(out + (size_t)row * 256);
            dst[k] = src[k];
        }
        __syncthreads();   // sh reused next iteration
    }
}

extern "C" void kernel_launch(void* const* d_in, const int* in_sizes, int n_in,
                              void* d_out, int out_size, void* d_ws, size_t ws_size,
                              hipStream_t stream) {
    const float* X = (const float*)d_in[0];
    const float* C = (const float*)d_in[1];
    float* out = (float*)d_out;
    const int N = in_sizes[0] / 256;

    // ws layout: [0,64) counter | [64,1088) c2f | [2048,4096) c2d | [4096,..) flag list
    unsigned* counter = (unsigned*)d_ws;
    float* c2f = (float*)((char*)d_ws + 64);
    double* c2d = (double*)((char*)d_ws + 2048);
    unsigned* list = (unsigned*)((char*)d_ws + 4096);
    unsigned cap = 0;
    if (ws_size > 4096) {
        size_t c = (ws_size - 4096) / 4;
        cap = (unsigned)(c < (size_t)CAP_MAX ? c : (size_t)CAP_MAX);
    }

    hipMemsetAsync(d_ws, 0, 64, stream);
    c2_kernel<<<1, 256, 0, stream>>>(C, c2f, c2d);
    score_kernel<<<N / TM, 256, 0, stream>>>(X, C, c2f, counter, list, cap, out);
    refine_kernel<<<1024, 256, 0, stream>>>(X, C, c2d, counter, list, cap, out);
}

// Round 2
// 627.728 us; speedup vs baseline: 1.3078x; 1.3078x over previous
//
#include <hip/hip_runtime.h>
#include <hip/hip_bf16.h>

// NegSamplerMiniBatch: out[n] = centroids[ idx of 2nd-largest distance(x_n,c_k) ]
// N=262144, D=256, K=256, f32.
//
// Rank key: s_k = |c_k|^2 - 2 x.c_k (monotone in distance). Dot via split-bf16
// MFMA: x = xh + xl, c = ch + cl (truncation splits); dot ~= xh.ch + xl.ch +
// xh.cl, f32 accumulate. Error <~1e-3 worst realistic; rows with top-3 gap
// < EPS=0.02 are exactly re-ranked in f64 by refine_kernel.

typedef __attribute__((ext_vector_type(8))) __bf16 bf16x8;
typedef __attribute__((ext_vector_type(4))) float f32x4;
typedef __attribute__((ext_vector_type(8))) unsigned short u16x8;

#define EPS 0.02f
#define CAP_MAX 65536
#define LROW 40   // padded LDS row stride in ushorts (80 B: 16B-aligned, 2-way banks)

__device__ __forceinline__ void split_f32(float v, unsigned short& hi, unsigned short& lo) {
    unsigned u = __float_as_uint(v);
    hi = (unsigned short)(u >> 16);                      // truncate to bf16
    float hif = __uint_as_float(u & 0xFFFF0000u);
    float lov = v - hif;                                 // exact residual
    lo = (unsigned short)(__float_as_uint(lov) >> 16);
}

__device__ __forceinline__ unsigned f32_key(float s) {   // order-preserving u32
    unsigned u = __float_as_uint(s);
    return u ^ ((unsigned)((int)u >> 31) | 0x80000000u);
}
__device__ __forceinline__ float key_to_float(unsigned key) {
    unsigned k = key & 0xFFFFFF00u;
    unsigned u = (k & 0x80000000u) ? (k ^ 0x80000000u) : ~k;
    return __uint_as_float(u);
}

// -------- one-time: C -> bf16 hi/lo in ws, plus c2 (f64 exact + f32) --------
__global__ __launch_bounds__(64) void cvt_kernel(const float* __restrict__ C,
    float* __restrict__ c2f, double* __restrict__ c2d,
    unsigned short* __restrict__ CHg, unsigned short* __restrict__ CLg) {
    const int k = blockIdx.x, l = threadIdx.x;
    float4 v = ((const float4*)(C + (size_t)k * 256))[l];
    unsigned short h0,h1,h2,h3, l0,l1,l2,l3;
    split_f32(v.x,h0,l0); split_f32(v.y,h1,l1); split_f32(v.z,h2,l2); split_f32(v.w,h3,l3);
    ((ushort4*)(CHg + (size_t)k * 256))[l] = make_ushort4(h0,h1,h2,h3);
    ((ushort4*)(CLg + (size_t)k * 256))[l] = make_ushort4(l0,l1,l2,l3);
    double s = (double)v.x*v.x + (double)v.y*v.y + (double)v.z*v.z + (double)v.w*v.w;
    #pragma unroll
    for (int off = 32; off >= 1; off >>= 1) s += __shfl_xor(s, off);
    if (l == 0) { c2f[k] = (float)s; c2d[k] = s; }
}

// -------- fused split-bf16 MFMA GEMM + top-3 + flag + gather-write --------
__global__ __launch_bounds__(256, 3) void score_kernel(
    const float* __restrict__ X, const unsigned short* __restrict__ CHg,
    const unsigned short* __restrict__ CLg, const float* __restrict__ C,
    const float* __restrict__ c2f, unsigned* __restrict__ counter,
    unsigned* __restrict__ list, unsigned cap, float* __restrict__ out) {

    // stage (ushort units): XH[64][40] XL[64][40] CH[256][40] CL[256][40] = 51200 B
    // epilogue overlay: KEY[64 rows][64 wslots][3] u32 = 49152 B
    __shared__ __align__(16) unsigned short SH[25600];
    __shared__ float c2s[256];
    __shared__ int bestIdx[64];

    unsigned short* XH  = SH;
    unsigned short* XL  = SH + 2560;
    unsigned short* CHl = SH + 5120;
    unsigned short* CLl = SH + 15360;

    const int t = threadIdx.x;
    const int rowBase = blockIdx.x * 64;
    c2s[t] = c2f[t];

    const int lane16 = t & 15, quad = (t >> 4) & 3, w = t >> 6;

    f32x4 acc[4][4];
    #pragma unroll
    for (int r = 0; r < 4; ++r)
        #pragma unroll
        for (int c = 0; c < 4; ++c) acc[r][c] = (f32x4)0.f;

    const int xr = t >> 2, xd = (t & 3) * 8;   // X stage: row 0..63, d-offset 0/8/16/24

    for (int chunk = 0; chunk < 8; ++chunk) {
        const int d0 = chunk * 32;
        // global loads into regs first
        const float4* gx = (const float4*)(X + (size_t)(rowBase + xr) * 256 + d0 + xd);
        float4 xa = gx[0], xb = gx[1];
        const u16x8* gh = (const u16x8*)(CHg + (size_t)t * 256 + d0);
        u16x8 ch0 = gh[0], ch1 = gh[1], ch2 = gh[2], ch3 = gh[3];
        const u16x8* gl = (const u16x8*)(CLg + (size_t)t * 256 + d0);
        u16x8 cl0 = gl[0], cl1 = gl[1], cl2 = gl[2], cl3 = gl[3];

        __syncthreads();   // previous chunk's frags consumed
        {
            union { u16x8 v; unsigned short s[8]; } hu, lu;
            float xv[8] = {xa.x, xa.y, xa.z, xa.w, xb.x, xb.y, xb.z, xb.w};
            #pragma unroll
            for (int q = 0; q < 8; ++q) split_f32(xv[q], hu.s[q], lu.s[q]);
            *(u16x8*)(XH + xr * LROW + xd) = hu.v;
            *(u16x8*)(XL + xr * LROW + xd) = lu.v;
        }
        *(u16x8*)(CHl + t * LROW +  0) = ch0;
        *(u16x8*)(CHl + t * LROW +  8) = ch1;
        *(u16x8*)(CHl + t * LROW + 16) = ch2;
        *(u16x8*)(CHl + t * LROW + 24) = ch3;
        *(u16x8*)(CLl + t * LROW +  0) = cl0;
        *(u16x8*)(CLl + t * LROW +  8) = cl1;
        *(u16x8*)(CLl + t * LROW + 16) = cl2;
        *(u16x8*)(CLl + t * LROW + 24) = cl3;
        __syncthreads();

        // A-frags: lane holds A[m=lane16][k=quad*8+j]
        bf16x8 ah[4], al[4];
        #pragma unroll
        for (int r = 0; r < 4; ++r) {
            ah[r] = *(const bf16x8*)(XH + (r * 16 + lane16) * LROW + quad * 8);
            al[r] = *(const bf16x8*)(XL + (r * 16 + lane16) * LROW + quad * 8);
        }
        #pragma unroll
        for (int c = 0; c < 4; ++c) {
            const int cb = (w * 64 + c * 16 + lane16) * LROW + quad * 8;
            bf16x8 bh = *(const bf16x8*)(CHl + cb);
            bf16x8 bl = *(const bf16x8*)(CLl + cb);
            #pragma unroll
            for (int r = 0; r < 4; ++r) {
                acc[r][c] = __builtin_amdgcn_mfma_f32_16x16x32_bf16(ah[r], bh, acc[r][c], 0, 0, 0);
                acc[r][c] = __builtin_amdgcn_mfma_f32_16x16x32_bf16(al[r], bh, acc[r][c], 0, 0, 0);
                acc[r][c] = __builtin_amdgcn_mfma_f32_16x16x32_bf16(ah[r], bl, acc[r][c], 0, 0, 0);
            }
        }
    }
    __syncthreads();   // stage dead; overlay KEY

    unsigned* KEY = (unsigned*)SH;   // [row][wslot][3], wslot = w*16+lane16

    // phase 1: per lane, top-3 over its 4 centroids, for each of its 16 rows
    float cc2[4];
    #pragma unroll
    for (int c = 0; c < 4; ++c) cc2[c] = c2s[w * 64 + c * 16 + lane16];
    #pragma unroll
    for (int r = 0; r < 4; ++r) {
        #pragma unroll
        for (int i = 0; i < 4; ++i) {
            const int row = r * 16 + quad * 4 + i;
            unsigned k1 = 0, k2 = 0, k3 = 0;   // all real keys > 0
            #pragma unroll
            for (int c = 0; c < 4; ++c) {
                float s = cc2[c] - 2.f * acc[r][c][i];
                unsigned cent = (unsigned)(w * 64 + c * 16 + lane16);
                unsigned key = (f32_key(s) & 0xFFFFFF00u) | (255u - cent);
                if (key > k1)      { k3 = k2; k2 = k1; k1 = key; }
                else if (key > k2) { k3 = k2; k2 = key; }
                else if (key > k3) { k3 = key; }
            }
            const int base = row * 192 + (w * 16 + lane16) * 3;
            KEY[base] = k1; KEY[base + 1] = k2; KEY[base + 2] = k3;
        }
    }
    __syncthreads();

    // phase 2: 4 threads per row, each merges 16 wslots (48 keys)
    {
        const int row = t & 63, qr = t >> 6;
        const int base = row * 192 + qr * 48;
        unsigned k1 = 0, k2 = 0, k3 = 0;
        for (int q = 0; q < 48; ++q) {
            unsigned key = KEY[base + q];
            if (key > k1)      { k3 = k2; k2 = k1; k1 = key; }
            else if (key > k2) { k3 = k2; k2 = key; }
            else if (key > k3) { k3 = key; }
        }
        KEY[base] = k1; KEY[base + 1] = k2; KEY[base + 2] = k3;
    }
    __syncthreads();

    // phase 3: one thread per row, final top-3 + gap flag
    if (t < 64) {
        unsigned k1 = 0, k2 = 0, k3 = 0;
        #pragma unroll
        for (int qr = 0; qr < 4; ++qr) {
            const int base = t * 192 + qr * 48;
            #pragma unroll
            for (int q = 0; q < 3; ++q) {
                unsigned key = KEY[base + q];
                if (key > k1)      { k3 = k2; k2 = k1; k1 = key; }
                else if (key > k2) { k3 = k2; k2 = key; }
                else if (key > k3) { k3 = key; }
            }
        }
        bestIdx[t] = 255 - (int)(k2 & 0xFFu);
        float s1 = key_to_float(k1), s2 = key_to_float(k2), s3 = key_to_float(k3);
        if (s1 - s2 < EPS || s2 - s3 < EPS) {
            unsigned p = atomicAdd(counter, 1u);
            if (p < cap) list[p] = (unsigned)(rowBase + t);
        }
    }
    __syncthreads();

    // gather-write: 4 threads per row, 16 float4 each
    {
        const int r = t >> 2, q0 = t & 3;
        const int c = bestIdx[r];
        const float4* src = (const float4*)(C + (size_t)c * 256);
        float4* dst = (float4*)(out + (size_t)(rowBase + r) * 256);
        #pragma unroll
        for (int q = 0; q < 16; ++q) dst[q0 + 4 * q] = src[q0 + 4 * q];
    }
}

// -------- exact f64 re-rank of flagged rows --------
__global__ __launch_bounds__(256) void refine_kernel(
    const float* __restrict__ X, const float* __restrict__ C,
    const double* __restrict__ c2d, const unsigned* __restrict__ counter,
    const unsigned* __restrict__ list, unsigned cap, float* __restrict__ out) {

    __shared__ float xs[256];
    __shared__ double sh[256];
    __shared__ int b2s;
    unsigned count = *counter;
    if (count > cap) count = cap;
    const int k = threadIdx.x;

    for (unsigned idx = blockIdx.x; idx < count; idx += gridDim.x) {
        const unsigned row = list[idx];
        xs[k] = X[(size_t)row * 256 + k];
        __syncthreads();
        const float4* cp = (const float4*)(C + (size_t)k * 256);
        double a = 0.0;
        #pragma unroll 4
        for (int j = 0; j < 64; ++j) {
            float4 c4 = cp[j];
            a += (double)c4.x * xs[4 * j + 0] + (double)c4.y * xs[4 * j + 1]
               + (double)c4.z * xs[4 * j + 2] + (double)c4.w * xs[4 * j + 3];
        }
        sh[k] = c2d[k] - 2.0 * a;
        __syncthreads();
        if (k == 0) {
            double b1 = -1e300, b2 = -1e300;
            int i1 = 0, i2 = 0;
            for (int q = 0; q < 256; ++q) {
                double s = sh[q];
                if (s > b1)      { b2 = b1; i2 = i1; b1 = s; i1 = q; }
                else if (s > b2) { b2 = s;  i2 = q; }
            }
            b2s = i2;
        }
        __syncthreads();
        const int csel = b2s;
        if (k < 64) {
            const float4* src = (const float4*)(C + (size_t)csel * 256);
            float4* dst = (float4*)(out + (size_t)row * 256);
            dst[k] = src[k];
        }
        __syncthreads();   // xs/sh reused next iteration
    }
}

extern "C" void kernel_launch(void* const* d_in, const int* in_sizes, int n_in,
                              void* d_out, int out_size, void* d_ws, size_t ws_size,
                              hipStream_t stream) {
    const float* X = (const float*)d_in[0];
    const float* C = (const float*)d_in[1];
    float* out = (float*)d_out;
    const int N = in_sizes[0] / 256;

    // ws: [0,64) counter | [64) c2f(1KB) | [2048) c2d(2KB) | [4096) CH(128KB)
    //     | [135168) CL(128KB) | [266240) flag list
    unsigned* counter = (unsigned*)d_ws;
    float* c2f = (float*)((char*)d_ws + 64);
    double* c2d = (double*)((char*)d_ws + 2048);
    unsigned short* CHg = (unsigned short*)((char*)d_ws + 4096);
    unsigned short* CLg = (unsigned short*)((char*)d_ws + 135168);
    unsigned* list = (unsigned*)((char*)d_ws + 266240);
    unsigned cap = 0;
    if (ws_size > 266240) {
        size_t c = (ws_size - 266240) / 4;
        cap = (unsigned)(c < (size_t)CAP_MAX ? c : (size_t)CAP_MAX);
    }

    hipMemsetAsync(d_ws, 0, 64, stream);
    cvt_kernel<<<256, 64, 0, stream>>>(C, c2f, c2d, CHg, CLg);
    score_kernel<<<N / 64, 256, 0, stream>>>(X, CHg, CLg, C, c2f, counter, list, cap, out);
    refine_kernel<<<1024, 256, 0, stream>>>(X, C, c2d, counter, list, cap, out);
}